// Round 5
// baseline (398.419 us; speedup 1.0000x reference)
//
#include <hip/hip_runtime.h>
#include <hip/hip_bf16.h>
#include <stdint.h>

typedef short bf16x8 __attribute__((ext_vector_type(8)));   // 8 bf16 in 4 VGPRs
typedef float f32x4 __attribute__((ext_vector_type(4)));
typedef unsigned short u16;
typedef u16 u16x8 __attribute__((ext_vector_type(8)));

__device__ __forceinline__ u16 f2bf(float x) {
  __hip_bfloat16 h = __float2bfloat16(x);
  return *reinterpret_cast<u16*>(&h);
}
__device__ __forceinline__ float bf2f(u16 v) {
  unsigned u = (unsigned)v << 16;
  return *reinterpret_cast<float*>(&u);
}

// async global->LDS, 16B per lane. LDS dest is wave-uniform base + lane*16 (m104/m108).
__device__ __forceinline__ void gload_lds16(const void* g, const void* lds_base) {
  __builtin_amdgcn_global_load_lds(
      (const __attribute__((address_space(1))) unsigned int*)(uintptr_t)g,
      (__attribute__((address_space(3))) unsigned int*)(uintptr_t)lds_base,
      16, 0, 0);
}

#define BAR() __builtin_amdgcn_s_barrier()
#define LG0() asm volatile("s_waitcnt lgkmcnt(0)" ::: "memory")
#define VM0() asm volatile("s_waitcnt vmcnt(0)" ::: "memory")

// ---------------- LayerNorm + cast to bf16 (rows of q,k,v) ----------------
__global__ __launch_bounds__(256) void ln_cast_kernel(
    const float* __restrict__ q, const float* __restrict__ k, const float* __restrict__ v,
    const float* __restrict__ lw, const float* __restrict__ lb, u16* __restrict__ out) {
  int row = blockIdx.x;
  const float* x;
  if (row < 8192) x = q + (size_t)row * 768;
  else if (row < 16384) x = k + (size_t)(row - 8192) * 768;
  else x = v + (size_t)(row - 16384) * 768;
  int t = threadIdx.x;
  float a0 = x[t], a1 = x[t + 256], a2 = x[t + 512];
  __shared__ float red[4];
  __shared__ float red2[4];
  float s = a0 + a1 + a2;
  for (int o = 32; o; o >>= 1) s += __shfl_down(s, o, 64);
  if ((t & 63) == 0) red[t >> 6] = s;
  __syncthreads();
  float mean = (red[0] + red[1] + red[2] + red[3]) * (1.0f / 768.0f);
  float d0 = a0 - mean, d1 = a1 - mean, d2 = a2 - mean;
  float vs = d0 * d0 + d1 * d1 + d2 * d2;
  for (int o = 32; o; o >>= 1) vs += __shfl_down(vs, o, 64);
  if ((t & 63) == 0) red2[t >> 6] = vs;
  __syncthreads();
  float var = (red2[0] + red2[1] + red2[2] + red2[3]) * (1.0f / 768.0f);
  float rstd = rsqrtf(var + 1e-5f);
  u16* o_ = out + (size_t)row * 768;
  o_[t]       = f2bf(d0 * rstd * lw[t]       + lb[t]);
  o_[t + 256] = f2bf(d1 * rstd * lw[t + 256] + lb[t + 256]);
  o_[t + 512] = f2bf(d2 * rstd * lw[t + 512] + lb[t + 512]);
}

// ---------------- fp32 -> bf16 cast (weights) ----------------
__global__ __launch_bounds__(256) void cast_f32_bf16(const float* __restrict__ in,
                                                     u16* __restrict__ out, int n4) {
  int i = blockIdx.x * 256 + threadIdx.x;
  if (i < n4) {
    float4 vv = ((const float4*)in)[i];
    ushort4 o;
    o.x = f2bf(vv.x); o.y = f2bf(vv.y); o.z = f2bf(vv.z); o.w = f2bf(vv.w);
    ((ushort4*)out)[i] = o;
  }
}

// ---------------- zero fp32 buffer ----------------
__global__ __launch_bounds__(256) void zero_f32(float* __restrict__ p, int n) {
  int i = blockIdx.x * 256 + threadIdx.x;
  if (i < n) p[i] = 0.0f;
}

// ---------------- 64x64 tiled bf16 transpose: vn[8192][768] -> vnT[768][8192] ----------------
__global__ __launch_bounds__(256) void transpose64(const u16* __restrict__ in, u16* __restrict__ out) {
  __shared__ __align__(16) u16 tile[64][72];
  int b = blockIdx.x;
  int tr = b / 12, tc = b % 12;
  int t = threadIdx.x;
  int r = t >> 3;
  int cb = (t & 7) << 3;
#pragma unroll
  for (int i = 0; i < 2; i++) {
    int row = r + i * 32;
    const u16* src = in + (size_t)(tr * 64 + row) * 768 + tc * 64 + cb;
    *(uint4*)&tile[row][cb] = *(const uint4*)src;
  }
  __syncthreads();
#pragma unroll
  for (int i = 0; i < 2; i++) {
    int oc = r + i * 32;
    u16x8 tmp;
#pragma unroll
    for (int j = 0; j < 8; j++) tmp[j] = tile[cb + j][oc];
    u16* dst = out + (size_t)(tc * 64 + oc) * 8192 + tr * 64 + cb;
    *(u16x8*)dst = tmp;
  }
}

// ---------------- sum 4 bf16 partials, scale by 1/rowsum, write bf16 ----------------
__global__ __launch_bounds__(256) void reduce4_scale(
    const u16* __restrict__ p0, const u16* __restrict__ p1,
    const u16* __restrict__ p2, const u16* __restrict__ p3,
    const float* __restrict__ rowsum, u16* __restrict__ out, int n8) {
  int i = blockIdx.x * 256 + threadIdx.x;
  if (i < n8) {
    float inv = 1.0f / rowsum[i / 96];
    u16x8 a = ((const u16x8*)p0)[i];
    u16x8 b = ((const u16x8*)p1)[i];
    u16x8 c = ((const u16x8*)p2)[i];
    u16x8 d = ((const u16x8*)p3)[i];
    u16x8 o;
#pragma unroll
    for (int j = 0; j < 8; j++)
      o[j] = f2bf((bf2f(a[j]) + bf2f(b[j]) + bf2f(c[j]) + bf2f(d[j])) * inv);
    ((u16x8*)out)[i] = o;
  }
}

// ================= QK^T + exp, 256x256 race-free pipelined kernel =================
// C[8192][8192] bf16 = exp(A[8192][768] @ B[8192][768]^T * scale); rowsum atomics.
// 512 thr = 8 waves (2M x 4N), per-wave 128x64 out, BK=64, 12 K-tiles.
// LDS 128 KiB: 2 buffers x (sA 32KB + sB 32KB). ALL staging targets the buffer NOT
// being read this K-tile (WAR-safe by construction; no reliance on load-landing timing).
// Stage distributed 2 calls/phase over 4 phases (fine interleave); one vmcnt(0)/tile.
// T2 swizzle byte^=((row&7)<<4) as involution: pre-swizzled source + swizzled ds_read.
__global__ __launch_bounds__(512, 2) void qk_exp_256(
    const u16* __restrict__ A, const u16* __restrict__ B, u16* __restrict__ C,
    float* __restrict__ rowsum, float scale) {
  __shared__ __align__(16) u16 sA[2][256 * 64];
  __shared__ __align__(16) u16 sB[2][256 * 64];
  // XCD swizzle: 1024 blocks, 1024 % 8 == 0
  int orig = blockIdx.x;
  int wg = (orig & 7) * 128 + (orig >> 3);
  int tm = wg >> 5, tn = wg & 31;
  const int t = threadIdx.x, l = t & 63, w = t >> 6;
  const int wr = w >> 2, wc = w & 3;     // 2 x 4 wave grid
  const int lr = l & 15, lq = l >> 4;
  const int colb = lq * 16;              // byte col within 64B half-k
  const int rswz = (lr & 7) << 4;        // read-side swizzle (row&7 == lr&7)

  f32x4 acc[8][4];
#pragma unroll
  for (int m = 0; m < 8; m++)
#pragma unroll
    for (int n = 0; n < 4; n++) acc[m][n] = (f32x4){0.f, 0.f, 0.f, 0.f};

  const size_t rA0 = (size_t)tm * 256, rB0 = (size_t)tn * 256;

  // one staging call: 512 threads x 16B = 8KB. idx 0..3 = A portion, 4..7 = B portion.
  // LDS layout per tile: [256 rows][128 bytes] linear; source col pre-swizzled (involution).
  auto SCALL = [&](int bufsel, int T, int idx) {
    const u16* src = (idx < 4) ? A : B;
    size_t r0 = (idx < 4) ? rA0 : rB0;
    u16* dstbase = (idx < 4) ? sA[bufsel] : sB[bufsel];
    int p = idx & 3, k0 = T << 6;
    int x = p * 8192 + t * 16;            // byte offset in the 32KB tile region
    int r = x >> 7;                        // row 0..255
    int cb = (x & 127) ^ ((r & 7) << 4);   // pre-swizzled source byte col
    gload_lds16((const char*)(src + (r0 + r) * 768 + k0) + cb,
                (const char*)dstbase + p * 8192 + w * 1024);  // wave-uniform base
  };
  auto LOADA = [&](bf16x8 (&aF)[4], int d, int mh, int kk) {
#pragma unroll
    for (int mf = 0; mf < 4; mf++) {
      int arow = wr * 128 + (mh * 4 + mf) * 16 + lr;
      int x = arow * 128 + kk * 64 + colb;
      aF[mf] = *(const bf16x8*)((const char*)sA[d] + (x ^ rswz));
    }
  };
  auto LOADB = [&](bf16x8 (&bF)[4], int d, int kk) {
#pragma unroll
    for (int nf = 0; nf < 4; nf++) {
      int brow = wc * 64 + nf * 16 + lr;
      int x = brow * 128 + kk * 64 + colb;
      bF[nf] = *(const bf16x8*)((const char*)sB[d] + (x ^ rswz));
    }
  };
  auto MM = [&](bf16x8 (&aF)[4], bf16x8 (&bF)[4], int mh) {
    __builtin_amdgcn_s_setprio(1);
#pragma unroll
    for (int mf = 0; mf < 4; mf++)
#pragma unroll
      for (int nf = 0; nf < 4; nf++)
        acc[mh * 4 + mf][nf] = __builtin_amdgcn_mfma_f32_16x16x32_bf16(
            aF[mf], bF[nf], acc[mh * 4 + mf][nf], 0, 0, 0);
    __builtin_amdgcn_s_setprio(0);
  };

  // ---- prologue: stage tile 0 into buf 0, drain, barrier ----
#pragma unroll
  for (int idx = 0; idx < 8; idx++) SCALL(0, 0, idx);
  VM0();
  BAR();

  // ---- main loop: tile T read from buf[T&1]; tile T+1 staged into buf[T&1]^1 ----
  for (int T = 0; T < 12; T++) {
    const int cur = T & 1, nxt = cur ^ 1;
    const bool pf = (T < 11);
    bf16x8 aF[4], bF0[4], bF1[4];
    // phase 1: (kk0, mh0) | stage A-h0 of T+1
    LOADA(aF, cur, 0, 0); LOADB(bF0, cur, 0);
    if (pf) { SCALL(nxt, T + 1, 0); SCALL(nxt, T + 1, 1); }
    BAR(); LG0(); MM(aF, bF0, 0); BAR();
    // phase 2: (kk0, mh1) | stage A-h1 of T+1
    LOADA(aF, cur, 1, 0);
    if (pf) { SCALL(nxt, T + 1, 2); SCALL(nxt, T + 1, 3); }
    BAR(); LG0(); MM(aF, bF0, 1); BAR();
    // phase 3: (kk1, mh0) | stage B-h0 of T+1
    LOADA(aF, cur, 0, 1); LOADB(bF1, cur, 1);
    if (pf) { SCALL(nxt, T + 1, 4); SCALL(nxt, T + 1, 5); }
    BAR(); LG0(); MM(aF, bF1, 0); BAR();
    // phase 4: (kk1, mh1) | stage B-h1 of T+1 | drain loads for next tile
    LOADA(aF, cur, 1, 1);
    if (pf) { SCALL(nxt, T + 1, 6); SCALL(nxt, T + 1, 7); }
    BAR(); LG0(); MM(aF, bF1, 1);
    VM0();
    BAR();
  }

  // ---- epilogue: exp + store + per-row sums (C/D layout: col=lane&15, row=(lane>>4)*4+j) ----
  float rs[8][4];
#pragma unroll
  for (int m = 0; m < 8; m++)
#pragma unroll
    for (int j = 0; j < 4; j++) rs[m][j] = 0.0f;
  const size_t rowBase = rA0 + (size_t)wr * 128;
  const int colBase = tn * 256 + wc * 64;
#pragma unroll
  for (int mi = 0; mi < 8; mi++) {
    size_t row0 = rowBase + mi * 16 + lq * 4;
#pragma unroll
    for (int nf = 0; nf < 4; nf++) {
      int col = colBase + nf * 16 + lr;
#pragma unroll
      for (int j = 0; j < 4; j++) {
        float e = __expf(acc[mi][nf][j] * scale);
        C[(row0 + j) * 8192 + col] = f2bf(e);
        rs[mi][j] += e;
      }
    }
  }
#pragma unroll
  for (int mi = 0; mi < 8; mi++)
#pragma unroll
    for (int j = 0; j < 4; j++) {
      float r = rs[mi][j];
      r += __shfl_xor(r, 1); r += __shfl_xor(r, 2);
      r += __shfl_xor(r, 4); r += __shfl_xor(r, 8);
      if (lr == 0) atomicAdd(&rowsum[rowBase + mi * 16 + lq * 4 + j], r);
    }
}

// ---------------- bt-GEMM (m97 128^2 structure) for qkv / PV / proj ----------------
// MODE 0: bf16 out * scale; MODE 2: f32 out + bias[col]
template <int MODE>
__global__ __launch_bounds__(256, 2) void gemm_bt(
    const u16* __restrict__ A0, const u16* __restrict__ B0,
    void* __restrict__ Cv0, void* __restrict__ Cv1,
    int M, int N, int K, int lda, int ldb, int ldc,
    float scale, const float* __restrict__ bias, size_t cSplitStride) {
  __shared__ __align__(16) u16 sA[128 * 64];
  __shared__ __align__(16) u16 sB[128 * 64];
  const int z = blockIdx.y;
  const u16* A = A0 + (size_t)z * (size_t)K;
  const u16* B = B0 + (size_t)z * (size_t)K;
  u16* Cb = (z < 2) ? ((u16*)Cv0 + (size_t)z * cSplitStride)
                    : ((u16*)Cv1 + (size_t)(z - 2) * cSplitStride);
  const int nTn = N >> 7;
  int nwg = gridDim.x, orig = blockIdx.x;
  int qq = nwg >> 3, rr = nwg & 7;
  int xcd = orig & 7, loc = orig >> 3;
  int wg = (xcd < rr ? xcd * (qq + 1) : rr * (qq + 1) + (xcd - rr) * qq) + loc;
  int tm = wg / nTn, tn = wg % nTn;

  const int t = threadIdx.x, l = t & 63, w = t >> 6;
  const int wr = w >> 1, wc = w & 1;
  const int lr = l & 15, kg = (l >> 4) << 3;

  f32x4 acc[4][4];
#pragma unroll
  for (int m = 0; m < 4; m++)
#pragma unroll
    for (int n = 0; n < 4; n++) acc[m][n] = (f32x4){0.f, 0.f, 0.f, 0.f};

  const size_t rowA0 = (size_t)tm * 128;
  const size_t rowB0 = (size_t)tn * 128;
  const int nk = K >> 6;
  for (int kt = 0; kt < nk; kt++) {
    const int k0 = kt << 6;
#pragma unroll
    for (int i = 0; i < 4; i++) {
      int chunk = i * 256 + t;
      int row = chunk >> 3;
      int col = (chunk & 7) << 3;
      gload_lds16(A + (rowA0 + row) * lda + k0 + col, (const char*)sA + (i * 256 + w * 64) * 16);
      gload_lds16(B + (rowB0 + row) * ldb + k0 + col, (const char*)sB + (i * 256 + w * 64) * 16);
    }
    __syncthreads();
#pragma unroll
    for (int kk = 0; kk < 2; kk++) {
      bf16x8 af[4], bfv[4];
#pragma unroll
      for (int m = 0; m < 4; m++)
        af[m] = *(const bf16x8*)&sA[(wr * 64 + m * 16 + lr) * 64 + kk * 32 + kg];
#pragma unroll
      for (int n = 0; n < 4; n++)
        bfv[n] = *(const bf16x8*)&sB[(wc * 64 + n * 16 + lr) * 64 + kk * 32 + kg];
#pragma unroll
      for (int m = 0; m < 4; m++)
#pragma unroll
        for (int n = 0; n < 4; n++)
          acc[m][n] = __builtin_amdgcn_mfma_f32_16x16x32_bf16(af[m], bfv[n], acc[m][n], 0, 0, 0);
    }
    __syncthreads();
  }
#pragma unroll
  for (int m = 0; m < 4; m++) {
    int row = tm * 128 + wr * 64 + m * 16 + ((l >> 4) << 2);
#pragma unroll
    for (int n = 0; n < 4; n++) {
      int col = tn * 128 + wc * 64 + n * 16 + lr;
#pragma unroll
      for (int j = 0; j < 4; j++) {
        float vl = acc[m][n][j];
        if (MODE == 0) Cb[(size_t)(row + j) * ldc + col] = f2bf(vl * scale);
        else ((float*)Cv0)[(size_t)(row + j) * ldc + col] = vl + bias[col];
      }
    }
  }
}

// ---------------- host ----------------
extern "C" void kernel_launch(void* const* d_in, const int* in_sizes, int n_in,
                              void* d_out, int out_size, void* d_ws, size_t ws_size,
                              hipStream_t stream) {
  const float* q  = (const float*)d_in[0];
  const float* k  = (const float*)d_in[1];
  const float* v  = (const float*)d_in[2];
  const float* lw = (const float*)d_in[3];
  const float* lb = (const float*)d_in[4];
  const float* Wq = (const float*)d_in[5];
  const float* Wp = (const float*)d_in[6];
  const float* bp = (const float*)d_in[7];

  char* ws = (char*)d_ws;
  size_t off = 0;
  auto alloc = [&](size_t b) { size_t o = off; off += (b + 255) & ~(size_t)255; return o; };
  size_t o_ln = alloc((size_t)24576 * 768 * 2);  // LN(q,k,v) bf16; later: vnT | p0 | p1
  size_t o_pj = alloc((size_t)24576 * 768 * 2);  // qn,kn,vn bf16; vn region later: rowsum
  size_t o_wq = alloc((size_t)768 * 768 * 2);
  size_t o_wp = alloc((size_t)768 * 768 * 2);
  u16* lnbuf = (u16*)(ws + o_ln);
  u16* pj    = (u16*)(ws + o_pj);
  u16* wqb   = (u16*)(ws + o_wq);
  u16* wpb   = (u16*)(ws + o_wp);
  const size_t NS = (size_t)8192 * 768;
  u16* vnT = lnbuf;
  u16* p0  = lnbuf + NS;
  u16* p1  = lnbuf + 2 * NS;
  float* rowsum = (float*)(pj + 2 * NS);  // vn rows dead after transpose
  u16* p2 = (u16*)d_out;                   // partials 2,3 in d_out (overwritten by proj)
  u16* p3 = p2 + NS;
  size_t fixedEnd = off;
  u16* Sbuf = (u16*)(ws + fixedEnd);       // P' = exp(S*scale) bf16, 8192x8192

  const float scale = 0.03608439182435161f;  // 1/sqrt(768)

  ln_cast_kernel<<<dim3(24576), dim3(256), 0, stream>>>(q, k, v, lw, lb, lnbuf);
  cast_f32_bf16<<<dim3(576), dim3(256), 0, stream>>>(Wq, wqb, 147456);
  cast_f32_bf16<<<dim3(576), dim3(256), 0, stream>>>(Wp, wpb, 147456);

  // qn/kn/vn = LN(x) @ W_qkv^T
  gemm_bt<0><<<dim3(1152), dim3(256), 0, stream>>>(lnbuf, wqb, (void*)pj, (void*)pj,
      24576, 768, 768, 768, 768, 768, 1.0f, (const float*)nullptr, 0);

  transpose64<<<dim3(1536), dim3(256), 0, stream>>>(pj + (size_t)16384 * 768, vnT);
  zero_f32<<<dim3(32), dim3(256), 0, stream>>>(rowsum, 8192);

  // P' = exp(qn @ kn^T * scale), rowsum via atomics — race-free 256^2 pipelined kernel
  qk_exp_256<<<dim3(1024), dim3(512), 0, stream>>>(pj, pj + NS, Sbuf, rowsum, scale);

  // attn partials = P' @ vn, 4-way split-K
  gemm_bt<0><<<dim3(384, 4), dim3(256), 0, stream>>>(
      Sbuf, vnT, (void*)p0, (void*)p2,
      8192, 768, 2048, 8192, 8192, 768, 1.0f, (const float*)nullptr, NS);

  // attn_out = (p0+p1+p2+p3) / rowsum
  reduce4_scale<<<dim3(3072), dim3(256), 0, stream>>>(p0, p1, p2, p3, rowsum, p0, (int)(NS / 8));

  // out = attn_out @ W_proj^T + b_proj
  gemm_bt<2><<<dim3(384), dim3(256), 0, stream>>>(p0, wpb, d_out, d_out,
      8192, 768, 768, 768, 768, 768, 1.0f, bp, 0);
}

// Round 6
// 362.490 us; speedup vs baseline: 1.0991x; 1.0991x over previous
//
#include <hip/hip_runtime.h>
#include <hip/hip_bf16.h>
#include <stdint.h>

typedef short bf16x8 __attribute__((ext_vector_type(8)));   // 8 bf16 in 4 VGPRs
typedef float f32x4 __attribute__((ext_vector_type(4)));
typedef unsigned short u16;
typedef u16 u16x8 __attribute__((ext_vector_type(8)));

__device__ __forceinline__ u16 f2bf(float x) {
  __hip_bfloat16 h = __float2bfloat16(x);
  return *reinterpret_cast<u16*>(&h);
}
__device__ __forceinline__ float bf2f(u16 v) {
  unsigned u = (unsigned)v << 16;
  return *reinterpret_cast<float*>(&u);
}

// async global->LDS, 16B per lane. LDS dest is wave-uniform base + lane*16 (m104/m108).
__device__ __forceinline__ void gload_lds16(const void* g, const void* lds_base) {
  __builtin_amdgcn_global_load_lds(
      (const __attribute__((address_space(1))) unsigned int*)(uintptr_t)g,
      (__attribute__((address_space(3))) unsigned int*)(uintptr_t)lds_base,
      16, 0, 0);
}

#define BAR() __builtin_amdgcn_s_barrier()

// ---------------- LayerNorm + cast to bf16 (rows of q,k,v) ----------------
__global__ __launch_bounds__(256) void ln_cast_kernel(
    const float* __restrict__ q, const float* __restrict__ k, const float* __restrict__ v,
    const float* __restrict__ lw, const float* __restrict__ lb, u16* __restrict__ out) {
  int row = blockIdx.x;
  const float* x;
  if (row < 8192) x = q + (size_t)row * 768;
  else if (row < 16384) x = k + (size_t)(row - 8192) * 768;
  else x = v + (size_t)(row - 16384) * 768;
  int t = threadIdx.x;
  float a0 = x[t], a1 = x[t + 256], a2 = x[t + 512];
  __shared__ float red[4];
  __shared__ float red2[4];
  float s = a0 + a1 + a2;
  for (int o = 32; o; o >>= 1) s += __shfl_down(s, o, 64);
  if ((t & 63) == 0) red[t >> 6] = s;
  __syncthreads();
  float mean = (red[0] + red[1] + red[2] + red[3]) * (1.0f / 768.0f);
  float d0 = a0 - mean, d1 = a1 - mean, d2 = a2 - mean;
  float vs = d0 * d0 + d1 * d1 + d2 * d2;
  for (int o = 32; o; o >>= 1) vs += __shfl_down(vs, o, 64);
  if ((t & 63) == 0) red2[t >> 6] = vs;
  __syncthreads();
  float var = (red2[0] + red2[1] + red2[2] + red2[3]) * (1.0f / 768.0f);
  float rstd = rsqrtf(var + 1e-5f);
  u16* o_ = out + (size_t)row * 768;
  o_[t]       = f2bf(d0 * rstd * lw[t]       + lb[t]);
  o_[t + 256] = f2bf(d1 * rstd * lw[t + 256] + lb[t + 256]);
  o_[t + 512] = f2bf(d2 * rstd * lw[t + 512] + lb[t + 512]);
}

// ---------------- fp32 -> bf16 cast (weights) ----------------
__global__ __launch_bounds__(256) void cast_f32_bf16(const float* __restrict__ in,
                                                     u16* __restrict__ out, int n4) {
  int i = blockIdx.x * 256 + threadIdx.x;
  if (i < n4) {
    float4 vv = ((const float4*)in)[i];
    ushort4 o;
    o.x = f2bf(vv.x); o.y = f2bf(vv.y); o.z = f2bf(vv.z); o.w = f2bf(vv.w);
    ((ushort4*)out)[i] = o;
  }
}

// ---------------- zero fp32 buffer ----------------
__global__ __launch_bounds__(256) void zero_f32(float* __restrict__ p, int n) {
  int i = blockIdx.x * 256 + threadIdx.x;
  if (i < n) p[i] = 0.0f;
}

// ---------------- 64x64 tiled bf16 transpose: vn[8192][768] -> vnT[768][8192] ----------------
__global__ __launch_bounds__(256) void transpose64(const u16* __restrict__ in, u16* __restrict__ out) {
  __shared__ __align__(16) u16 tile[64][72];
  int b = blockIdx.x;
  int tr = b / 12, tc = b % 12;
  int t = threadIdx.x;
  int r = t >> 3;
  int cb = (t & 7) << 3;
#pragma unroll
  for (int i = 0; i < 2; i++) {
    int row = r + i * 32;
    const u16* src = in + (size_t)(tr * 64 + row) * 768 + tc * 64 + cb;
    *(uint4*)&tile[row][cb] = *(const uint4*)src;
  }
  __syncthreads();
#pragma unroll
  for (int i = 0; i < 2; i++) {
    int oc = r + i * 32;
    u16x8 tmp;
#pragma unroll
    for (int j = 0; j < 8; j++) tmp[j] = tile[cb + j][oc];
    u16* dst = out + (size_t)(tc * 64 + oc) * 8192 + tr * 64 + cb;
    *(u16x8*)dst = tmp;
  }
}

// ---------------- sum 4 bf16 partials, scale by 1/rowsum, write bf16 ----------------
__global__ __launch_bounds__(256) void reduce4_scale(
    const u16* __restrict__ p0, const u16* __restrict__ p1,
    const u16* __restrict__ p2, const u16* __restrict__ p3,
    const float* __restrict__ rowsum, u16* __restrict__ out, int n8) {
  int i = blockIdx.x * 256 + threadIdx.x;
  if (i < n8) {
    float inv = 1.0f / rowsum[i / 96];
    u16x8 a = ((const u16x8*)p0)[i];
    u16x8 b = ((const u16x8*)p1)[i];
    u16x8 c = ((const u16x8*)p2)[i];
    u16x8 d = ((const u16x8*)p3)[i];
    u16x8 o;
#pragma unroll
    for (int j = 0; j < 8; j++)
      o[j] = f2bf((bf2f(a[j]) + bf2f(b[j]) + bf2f(c[j]) + bf2f(d[j])) * inv);
    ((u16x8*)out)[i] = o;
  }
}

// ========== QK^T + exp, 256x256 tile, BK=32, 4-deep LDS rotation, counted vmcnt ==========
// C[8192][8192] bf16 = exp(A @ B^T * scale); rowsum atomics.
// 512 thr = 8 waves (2M x 4N), per-wave 128x64 out. 24 K-tiles of 32.
// Phase T: ds_read buf[T&3] | stage tile T+2 -> buf[(T+2)&3] | BAR | 32 MFMA | vmcnt(4) | BAR.
// RAW: vmcnt(4) at end of T-1 guarantees tile T landed (only tile T+1's 4 loads outstanding).
// WAR: buf[(T+2)&3] last read at phase T-2; stage ISSUES >=3 barriers after those reads
//      completed, and an LDS write cannot land before its instruction issues.
// Swizzle (64B rows): byte ^= (((row>>1)&3)<<4) -> exactly 2-way banks (free) on reads;
// applied as involution: pre-swizzled global source col + swizzled ds_read addr (rule 21).
__global__ __launch_bounds__(512, 2) void qk_exp_256(
    const u16* __restrict__ A, const u16* __restrict__ B, u16* __restrict__ C,
    float* __restrict__ rowsum, float scale) {
  __shared__ __align__(16) u16 sA[4][256 * 32];   // 4 bufs x 16 KB
  __shared__ __align__(16) u16 sB[4][256 * 32];
  // XCD-chunked + per-XCD 2D ordering: xcd owns tm in [xcd*4, xcd*4+4), sweeps tn with
  // 4 tm's stacked per tn (B panel reused consecutively; 4 A panels stay L2-resident).
  int orig = blockIdx.x;               // 1024 blocks, %8==0
  int xcd = orig & 7, i = orig >> 3;   // i in 0..127
  int tm = xcd * 4 + (i & 3), tn = i >> 2;
  const int t = threadIdx.x, l = t & 63, w = t >> 6;
  const int wr = w >> 2, wc = w & 3;   // 2 x 4 wave grid
  const int lr = l & 15, lq = l >> 4;
  const int colb = lq * 16;            // byte col within 64B row

  f32x4 acc[8][4];
#pragma unroll
  for (int m = 0; m < 8; m++)
#pragma unroll
    for (int n = 0; n < 4; n++) acc[m][n] = (f32x4){0.f, 0.f, 0.f, 0.f};

  const size_t rA0 = (size_t)tm * 256, rB0 = (size_t)tn * 256;

  // one staging call = 8KB = 128 rows x 64B. idx: 0,1 = A halves; 2,3 = B halves.
  auto SCALL = [&](int b, int Tn, int idx) {
    const u16* src = (idx < 2) ? A : B;
    size_t r0 = (idx < 2) ? rA0 : rB0;
    char* dst = (char*)((idx < 2) ? sA[b] : sB[b]);
    int p = idx & 1;
    int x = p * 8192 + t * 16;                  // linear byte offset in 16KB tile
    int r = x >> 6;                             // row 0..255
    int cb = (x & 63) ^ (((r >> 1) & 3) << 4);  // pre-swizzled source byte col
    gload_lds16((const char*)(src + (r0 + r) * 768 + (Tn << 5)) + cb,
                dst + p * 8192 + w * 1024);     // wave-uniform base + lane*16
  };
  auto LOADA = [&](bf16x8 (&aF)[4], int d, int mh) {
#pragma unroll
    for (int mf = 0; mf < 4; mf++) {
      int row = wr * 128 + (mh * 4 + mf) * 16 + lr;
      int x = row * 64 + colb;
      aF[mf] = *(const bf16x8*)((const char*)sA[d] + (x ^ (((row >> 1) & 3) << 4)));
    }
  };
  auto LOADB = [&](bf16x8 (&bF)[4], int d) {
#pragma unroll
    for (int nf = 0; nf < 4; nf++) {
      int row = wc * 64 + nf * 16 + lr;
      int x = row * 64 + colb;
      bF[nf] = *(const bf16x8*)((const char*)sB[d] + (x ^ (((row >> 1) & 3) << 4)));
    }
  };
  auto MM = [&](bf16x8 (&aF)[4], bf16x8 (&bF)[4], int mh) {
    __builtin_amdgcn_s_setprio(1);
#pragma unroll
    for (int mf = 0; mf < 4; mf++)
#pragma unroll
      for (int nf = 0; nf < 4; nf++)
        acc[mh * 4 + mf][nf] = __builtin_amdgcn_mfma_f32_16x16x32_bf16(
            aF[mf], bF[nf], acc[mh * 4 + mf][nf], 0, 0, 0);
    __builtin_amdgcn_s_setprio(0);
  };

  // ---- prologue: stage tiles 0,1; wait for tile 0 (leave tile 1's 4 in flight) ----
#pragma unroll
  for (int idx = 0; idx < 4; idx++) SCALL(0, 0, idx);
#pragma unroll
  for (int idx = 0; idx < 4; idx++) SCALL(1, 1, idx);
  asm volatile("s_waitcnt vmcnt(4)" ::: "memory");
  BAR();

  // ---- main loop: 24 phases ----
#pragma unroll 4
  for (int T = 0; T < 24; T++) {
    const int cur = T & 3;
    bf16x8 aF[4], bF[4];
    LOADA(aF, cur, 0);
    LOADB(bF, cur);
    if (T + 2 < 24) {
      const int nb = (T + 2) & 3;
      SCALL(nb, T + 2, 0); SCALL(nb, T + 2, 1);
      SCALL(nb, T + 2, 2); SCALL(nb, T + 2, 3);
    }
    BAR();
    MM(aF, bF, 0);
    bf16x8 aG[4];
    LOADA(aG, cur, 1);
    MM(aG, bF, 1);
    if (T < 22) { asm volatile("s_waitcnt vmcnt(4)" ::: "memory"); }
    else        { asm volatile("s_waitcnt vmcnt(0)" ::: "memory"); }
    BAR();
  }

  // ---- epilogue: exp + store + per-row sums (C/D layout: col=lane&15, row=(lane>>4)*4+j) ----
  float rs[8][4];
#pragma unroll
  for (int m = 0; m < 8; m++)
#pragma unroll
    for (int j = 0; j < 4; j++) rs[m][j] = 0.0f;
  const size_t rowBase = rA0 + (size_t)wr * 128;
  const int colBase = tn * 256 + wc * 64;
#pragma unroll
  for (int mi = 0; mi < 8; mi++) {
    size_t row0 = rowBase + mi * 16 + lq * 4;
#pragma unroll
    for (int nf = 0; nf < 4; nf++) {
      int col = colBase + nf * 16 + lr;
#pragma unroll
      for (int j = 0; j < 4; j++) {
        float e = __expf(acc[mi][nf][j] * scale);
        C[(row0 + j) * 8192 + col] = f2bf(e);
        rs[mi][j] += e;
      }
    }
  }
#pragma unroll
  for (int mi = 0; mi < 8; mi++)
#pragma unroll
    for (int j = 0; j < 4; j++) {
      float r = rs[mi][j];
      r += __shfl_xor(r, 1); r += __shfl_xor(r, 2);
      r += __shfl_xor(r, 4); r += __shfl_xor(r, 8);
      if (lr == 0) atomicAdd(&rowsum[rowBase + mi * 16 + lq * 4 + j], r);
    }
}

// ---------------- bt-GEMM (m97 128^2 structure) for qkv / PV / proj ----------------
// MODE 0: bf16 out * scale; MODE 2: f32 out + bias[col]
template <int MODE>
__global__ __launch_bounds__(256, 2) void gemm_bt(
    const u16* __restrict__ A0, const u16* __restrict__ B0,
    void* __restrict__ Cv0, void* __restrict__ Cv1,
    int M, int N, int K, int lda, int ldb, int ldc,
    float scale, const float* __restrict__ bias, size_t cSplitStride) {
  __shared__ __align__(16) u16 sA[128 * 64];
  __shared__ __align__(16) u16 sB[128 * 64];
  const int z = blockIdx.y;
  const u16* A = A0 + (size_t)z * (size_t)K;
  const u16* B = B0 + (size_t)z * (size_t)K;
  u16* Cb = (z < 2) ? ((u16*)Cv0 + (size_t)z * cSplitStride)
                    : ((u16*)Cv1 + (size_t)(z - 2) * cSplitStride);
  const int nTn = N >> 7;
  int nwg = gridDim.x, orig = blockIdx.x;
  int qq = nwg >> 3, rr = nwg & 7;
  int xcd = orig & 7, loc = orig >> 3;
  int wg = (xcd < rr ? xcd * (qq + 1) : rr * (qq + 1) + (xcd - rr) * qq) + loc;
  int tm = wg / nTn, tn = wg % nTn;

  const int t = threadIdx.x, l = t & 63, w = t >> 6;
  const int wr = w >> 1, wc = w & 1;
  const int lr = l & 15, kg = (l >> 4) << 3;

  f32x4 acc[4][4];
#pragma unroll
  for (int m = 0; m < 4; m++)
#pragma unroll
    for (int n = 0; n < 4; n++) acc[m][n] = (f32x4){0.f, 0.f, 0.f, 0.f};

  const size_t rowA0 = (size_t)tm * 128;
  const size_t rowB0 = (size_t)tn * 128;
  const int nk = K >> 6;
  for (int kt = 0; kt < nk; kt++) {
    const int k0 = kt << 6;
#pragma unroll
    for (int i = 0; i < 4; i++) {
      int chunk = i * 256 + t;
      int row = chunk >> 3;
      int col = (chunk & 7) << 3;
      gload_lds16(A + (rowA0 + row) * lda + k0 + col, (const char*)sA + (i * 256 + w * 64) * 16);
      gload_lds16(B + (rowB0 + row) * ldb + k0 + col, (const char*)sB + (i * 256 + w * 64) * 16);
    }
    __syncthreads();
#pragma unroll
    for (int kk = 0; kk < 2; kk++) {
      bf16x8 af[4], bfv[4];
#pragma unroll
      for (int m = 0; m < 4; m++)
        af[m] = *(const bf16x8*)&sA[(wr * 64 + m * 16 + lr) * 64 + kk * 32 + kg];
#pragma unroll
      for (int n = 0; n < 4; n++)
        bfv[n] = *(const bf16x8*)&sB[(wc * 64 + n * 16 + lr) * 64 + kk * 32 + kg];
#pragma unroll
      for (int m = 0; m < 4; m++)
#pragma unroll
        for (int n = 0; n < 4; n++)
          acc[m][n] = __builtin_amdgcn_mfma_f32_16x16x32_bf16(af[m], bfv[n], acc[m][n], 0, 0, 0);
    }
    __syncthreads();
  }
#pragma unroll
  for (int m = 0; m < 4; m++) {
    int row = tm * 128 + wr * 64 + m * 16 + ((l >> 4) << 2);
#pragma unroll
    for (int n = 0; n < 4; n++) {
      int col = tn * 128 + wc * 64 + n * 16 + lr;
#pragma unroll
      for (int j = 0; j < 4; j++) {
        float vl = acc[m][n][j];
        if (MODE == 0) Cb[(size_t)(row + j) * ldc + col] = f2bf(vl * scale);
        else ((float*)Cv0)[(size_t)(row + j) * ldc + col] = vl + bias[col];
      }
    }
  }
}

// ---------------- host ----------------
extern "C" void kernel_launch(void* const* d_in, const int* in_sizes, int n_in,
                              void* d_out, int out_size, void* d_ws, size_t ws_size,
                              hipStream_t stream) {
  const float* q  = (const float*)d_in[0];
  const float* k  = (const float*)d_in[1];
  const float* v  = (const float*)d_in[2];
  const float* lw = (const float*)d_in[3];
  const float* lb = (const float*)d_in[4];
  const float* Wq = (const float*)d_in[5];
  const float* Wp = (const float*)d_in[6];
  const float* bp = (const float*)d_in[7];

  char* ws = (char*)d_ws;
  size_t off = 0;
  auto alloc = [&](size_t b) { size_t o = off; off += (b + 255) & ~(size_t)255; return o; };
  size_t o_ln = alloc((size_t)24576 * 768 * 2);  // LN(q,k,v) bf16; later: vnT | p0 | p1
  size_t o_pj = alloc((size_t)24576 * 768 * 2);  // qn,kn,vn bf16; vn region later: rowsum
  size_t o_wq = alloc((size_t)768 * 768 * 2);
  size_t o_wp = alloc((size_t)768 * 768 * 2);
  u16* lnbuf = (u16*)(ws + o_ln);
  u16* pj    = (u16*)(ws + o_pj);
  u16* wqb   = (u16*)(ws + o_wq);
  u16* wpb   = (u16*)(ws + o_wp);
  const size_t NS = (size_t)8192 * 768;
  u16* vnT = lnbuf;
  u16* p0  = lnbuf + NS;
  u16* p1  = lnbuf + 2 * NS;
  float* rowsum = (float*)(pj + 2 * NS);  // vn rows dead after transpose
  u16* p2 = (u16*)d_out;                   // partials 2,3 in d_out (overwritten by proj)
  u16* p3 = p2 + NS;
  size_t fixedEnd = off;
  u16* Sbuf = (u16*)(ws + fixedEnd);       // P' = exp(S*scale) bf16, 8192x8192

  const float scale = 0.03608439182435161f;  // 1/sqrt(768)

  ln_cast_kernel<<<dim3(24576), dim3(256), 0, stream>>>(q, k, v, lw, lb, lnbuf);
  cast_f32_bf16<<<dim3(576), dim3(256), 0, stream>>>(Wq, wqb, 147456);
  cast_f32_bf16<<<dim3(576), dim3(256), 0, stream>>>(Wp, wpb, 147456);

  // qn/kn/vn = LN(x) @ W_qkv^T
  gemm_bt<0><<<dim3(1152), dim3(256), 0, stream>>>(lnbuf, wqb, (void*)pj, (void*)pj,
      24576, 768, 768, 768, 768, 768, 1.0f, (const float*)nullptr, 0);

  transpose64<<<dim3(1536), dim3(256), 0, stream>>>(pj + (size_t)16384 * 768, vnT);
  zero_f32<<<dim3(32), dim3(256), 0, stream>>>(rowsum, 8192);

  // P' = exp(qn @ kn^T * scale), rowsum via atomics — BK=32 4-deep counted-vmcnt kernel
  qk_exp_256<<<dim3(1024), dim3(512), 0, stream>>>(pj, pj + NS, Sbuf, rowsum, scale);

  // attn partials = P' @ vn, 4-way split-K
  gemm_bt<0><<<dim3(384, 4), dim3(256), 0, stream>>>(
      Sbuf, vnT, (void*)p0, (void*)p2,
      8192, 768, 2048, 8192, 8192, 768, 1.0f, (const float*)nullptr, NS);

  // attn_out = (p0+p1+p2+p3) / rowsum
  reduce4_scale<<<dim3(3072), dim3(256), 0, stream>>>(p0, p1, p2, p3, rowsum, p0, (int)(NS / 8));

  // out = attn_out @ W_proj^T + b_proj
  gemm_bt<2><<<dim3(384), dim3(256), 0, stream>>>(p0, wpb, d_out, d_out,
      8192, 768, 768, 768, 768, 768, 1.0f, bp, 0);
}

// Round 8
// 359.419 us; speedup vs baseline: 1.1085x; 1.0085x over previous
//
#include <hip/hip_runtime.h>
#include <hip/hip_bf16.h>
#include <stdint.h>

typedef short bf16x8 __attribute__((ext_vector_type(8)));   // 8 bf16 in 4 VGPRs
typedef float f32x4 __attribute__((ext_vector_type(4)));
typedef unsigned short u16;
typedef u16 u16x8 __attribute__((ext_vector_type(8)));

__device__ __forceinline__ u16 f2bf(float x) {
  __hip_bfloat16 h = __float2bfloat16(x);
  return *reinterpret_cast<u16*>(&h);
}
__device__ __forceinline__ float bf2f(u16 v) {
  unsigned u = (unsigned)v << 16;
  return *reinterpret_cast<float*>(&u);
}

// async global->LDS, 16B per lane. LDS dest is wave-uniform base + lane*16 (m104/m108).
__device__ __forceinline__ void gload_lds16(const void* g, const void* lds_base) {
  __builtin_amdgcn_global_load_lds(
      (const __attribute__((address_space(1))) unsigned int*)(uintptr_t)g,
      (__attribute__((address_space(3))) unsigned int*)(uintptr_t)lds_base,
      16, 0, 0);
}

#define BAR() __builtin_amdgcn_s_barrier()

// ---------------- LayerNorm + cast to bf16 (rows of q,k,v) ----------------
__global__ __launch_bounds__(256) void ln_cast_kernel(
    const float* __restrict__ q, const float* __restrict__ k, const float* __restrict__ v,
    const float* __restrict__ lw, const float* __restrict__ lb, u16* __restrict__ out) {
  int row = blockIdx.x;
  const float* x;
  if (row < 8192) x = q + (size_t)row * 768;
  else if (row < 16384) x = k + (size_t)(row - 8192) * 768;
  else x = v + (size_t)(row - 16384) * 768;
  int t = threadIdx.x;
  float a0 = x[t], a1 = x[t + 256], a2 = x[t + 512];
  __shared__ float red[4];
  __shared__ float red2[4];
  float s = a0 + a1 + a2;
  for (int o = 32; o; o >>= 1) s += __shfl_down(s, o, 64);
  if ((t & 63) == 0) red[t >> 6] = s;
  __syncthreads();
  float mean = (red[0] + red[1] + red[2] + red[3]) * (1.0f / 768.0f);
  float d0 = a0 - mean, d1 = a1 - mean, d2 = a2 - mean;
  float vs = d0 * d0 + d1 * d1 + d2 * d2;
  for (int o = 32; o; o >>= 1) vs += __shfl_down(vs, o, 64);
  if ((t & 63) == 0) red2[t >> 6] = vs;
  __syncthreads();
  float var = (red2[0] + red2[1] + red2[2] + red2[3]) * (1.0f / 768.0f);
  float rstd = rsqrtf(var + 1e-5f);
  u16* o_ = out + (size_t)row * 768;
  o_[t]       = f2bf(d0 * rstd * lw[t]       + lb[t]);
  o_[t + 256] = f2bf(d1 * rstd * lw[t + 256] + lb[t + 256]);
  o_[t + 512] = f2bf(d2 * rstd * lw[t + 512] + lb[t + 512]);
}

// ---------------- fp32 -> bf16 cast (weights) ----------------
__global__ __launch_bounds__(256) void cast_f32_bf16(const float* __restrict__ in,
                                                     u16* __restrict__ out, int n4) {
  int i = blockIdx.x * 256 + threadIdx.x;
  if (i < n4) {
    float4 vv = ((const float4*)in)[i];
    ushort4 o;
    o.x = f2bf(vv.x); o.y = f2bf(vv.y); o.z = f2bf(vv.z); o.w = f2bf(vv.w);
    ((ushort4*)out)[i] = o;
  }
}

// ---------------- zero fp32 buffer ----------------
__global__ __launch_bounds__(256) void zero_f32(float* __restrict__ p, int n) {
  int i = blockIdx.x * 256 + threadIdx.x;
  if (i < n) p[i] = 0.0f;
}

// ---------------- 64x64 tiled bf16 transpose: vn[8192][768] -> vnT[768][8192] ----------------
__global__ __launch_bounds__(256) void transpose64(const u16* __restrict__ in, u16* __restrict__ out) {
  __shared__ __align__(16) u16 tile[64][72];
  int b = blockIdx.x;
  int tr = b / 12, tc = b % 12;
  int t = threadIdx.x;
  int r = t >> 3;
  int cb = (t & 7) << 3;
#pragma unroll
  for (int i = 0; i < 2; i++) {
    int row = r + i * 32;
    const u16* src = in + (size_t)(tr * 64 + row) * 768 + tc * 64 + cb;
    *(uint4*)&tile[row][cb] = *(const uint4*)src;
  }
  __syncthreads();
#pragma unroll
  for (int i = 0; i < 2; i++) {
    int oc = r + i * 32;
    u16x8 tmp;
#pragma unroll
    for (int j = 0; j < 8; j++) tmp[j] = tile[cb + j][oc];
    u16* dst = out + (size_t)(tc * 64 + oc) * 8192 + tr * 64 + cb;
    *(u16x8*)dst = tmp;
  }
}

// ---------------- sum 4 bf16 partials, scale by 1/rowsum, write bf16 ----------------
__global__ __launch_bounds__(256) void reduce4_scale(
    const u16* __restrict__ p0, const u16* __restrict__ p1,
    const u16* __restrict__ p2, const u16* __restrict__ p3,
    const float* __restrict__ rowsum, u16* __restrict__ out, int n8) {
  int i = blockIdx.x * 256 + threadIdx.x;
  if (i < n8) {
    float inv = 1.0f / rowsum[i / 96];
    u16x8 a = ((const u16x8*)p0)[i];
    u16x8 b = ((const u16x8*)p1)[i];
    u16x8 c = ((const u16x8*)p2)[i];
    u16x8 d = ((const u16x8*)p3)[i];
    u16x8 o;
#pragma unroll
    for (int j = 0; j < 8; j++)
      o[j] = f2bf((bf2f(a[j]) + bf2f(b[j]) + bf2f(c[j]) + bf2f(d[j])) * inv);
    ((u16x8*)out)[i] = o;
  }
}

// ========== QK^T + exp, 256x256 tile, BK=32, 4-deep rotation, stage-ahead-3 ==========
// C[8192][8192] bf16 = exp(A @ B^T * scale); rowsum atomics.
// 512 thr = 8 waves (2M x 4N), per-wave 128x64 out. 24 K-tiles of 32.
// Phase T: ds_read buf[T&3] | stage tile T+3 -> buf[(T+3)&3] | BAR | 32 MFMA | vmcnt(8) | BAR.
// RAW: at phase-T start outstanding = 8 = tiles {T+1,T+2}; vmcnt(8) at end of T-1 forced
//      tile T complete. WAR: buf[(T+3)&3] last read in phase T-1; stage issues after that
//      phase's closing barrier, and an LDS write cannot land before its instruction issues.
// SINGLE merged LDS array (round-7 NaN root cause: separate sA/sB arrays have NO
// guaranteed adjacency; B staging assumed sB at sA+64KB). A at byte 0, B at byte 65536.
// Swizzle (64B rows): byte ^= (((row>>1)&3)<<4), involution on both sides (rule 21).
__global__ __launch_bounds__(512, 2) void qk_exp_256(
    const u16* __restrict__ A, const u16* __restrict__ B, u16* __restrict__ C,
    float* __restrict__ rowsum, float scale) {
  __shared__ __align__(16) u16 lds[8 * 256 * 32];  // 128 KB: A bufs 0-3 | B bufs 0-3
  // XCD-chunked 2D ordering: xcd owns 4 consecutive tm, sweeps tn (A panels L2-resident).
  int orig = blockIdx.x;               // 1024 blocks, %8==0
  int xcd = orig & 7, i = orig >> 3;
  int tm = xcd * 4 + (i & 3), tn = i >> 2;
  const int t = threadIdx.x, l = t & 63, w = t >> 6;
  const int wr = w >> 2, wc = w & 3;   // 2 x 4 wave grid
  const int lr = l & 15, lq = l >> 4;
  const int colb = lq * 16;

  f32x4 acc[8][4];
#pragma unroll
  for (int m = 0; m < 8; m++)
#pragma unroll
    for (int n = 0; n < 4; n++) acc[m][n] = (f32x4){0.f, 0.f, 0.f, 0.f};

  const size_t rA0 = (size_t)tm * 256, rB0 = (size_t)tn * 256;

  // ---- hoisted addressing ----
  const char* gsrc[4];   // per-lane global source addr at tile 0 (idx: 0,1=A halves; 2,3=B)
  int ldsoff[4];         // dest offset: region base + half offset + wave chunk
#pragma unroll
  for (int idx = 0; idx < 4; idx++) {
    const u16* src = (idx < 2) ? A : B;
    size_t r0 = (idx < 2) ? rA0 : rB0;
    int p = idx & 1;
    int x = p * 8192 + t * 16;                  // linear byte offset in 16KB tile
    int r = x >> 6;                             // row 0..255
    int cb = (x & 63) ^ (((r >> 1) & 3) << 4);  // pre-swizzled source byte col
    gsrc[idx] = (const char*)(src + (r0 + r) * 768) + cb;
    ldsoff[idx] = ((idx < 2) ? 0 : 65536) + p * 8192 + w * 1024;
  }
  int offA[2][4], offB[4];                      // swizzled LDS read byte offsets (buf 0)
#pragma unroll
  for (int mh = 0; mh < 2; mh++)
#pragma unroll
    for (int mf = 0; mf < 4; mf++) {
      int row = wr * 128 + (mh * 4 + mf) * 16 + lr;
      int x = row * 64 + colb;
      offA[mh][mf] = x ^ (((row >> 1) & 3) << 4);
    }
#pragma unroll
  for (int nf = 0; nf < 4; nf++) {
    int row = wc * 64 + nf * 16 + lr;
    int x = row * 64 + colb;
    offB[nf] = 65536 + (x ^ (((row >> 1) & 3) << 4));
  }

#define SCALL(BUF, TT, IDX)                                                  \
  gload_lds16(gsrc[IDX] + (size_t)(TT) * 64,                                 \
              (const char*)lds + (BUF) * 16384 + ldsoff[IDX])

  auto LOADA = [&](bf16x8 (&aF)[4], int b, int mh) {
#pragma unroll
    for (int mf = 0; mf < 4; mf++)
      aF[mf] = *(const bf16x8*)((const char*)lds + b * 16384 + offA[mh][mf]);
  };
  auto LOADB = [&](bf16x8 (&bF)[4], int b) {
#pragma unroll
    for (int nf = 0; nf < 4; nf++)
      bF[nf] = *(const bf16x8*)((const char*)lds + b * 16384 + offB[nf]);
  };
  auto MM = [&](bf16x8 (&aF)[4], bf16x8 (&bF)[4], int mh) {
    __builtin_amdgcn_s_setprio(1);
#pragma unroll
    for (int mf = 0; mf < 4; mf++)
#pragma unroll
      for (int nf = 0; nf < 4; nf++)
        acc[mh * 4 + mf][nf] = __builtin_amdgcn_mfma_f32_16x16x32_bf16(
            aF[mf], bF[nf], acc[mh * 4 + mf][nf], 0, 0, 0);
    __builtin_amdgcn_s_setprio(0);
  };

#define PHASE(CUR, SBUF, STAGET, DOSTAGE, VMN)                               \
  do {                                                                       \
    bf16x8 aF[4], bF[4], aG[4];                                              \
    LOADA(aF, CUR, 0);                                                       \
    LOADB(bF, CUR);                                                          \
    if (DOSTAGE) {                                                           \
      SCALL(SBUF, STAGET, 0); SCALL(SBUF, STAGET, 1);                        \
      SCALL(SBUF, STAGET, 2); SCALL(SBUF, STAGET, 3);                        \
    }                                                                        \
    BAR();                                                                   \
    MM(aF, bF, 0);                                                           \
    LOADA(aG, CUR, 1);                                                       \
    MM(aG, bF, 1);                                                           \
    if ((VMN) == 8) asm volatile("s_waitcnt vmcnt(8)" ::: "memory");         \
    else if ((VMN) == 4) asm volatile("s_waitcnt vmcnt(4)" ::: "memory");    \
    else if ((VMN) == 0) asm volatile("s_waitcnt vmcnt(0)" ::: "memory");    \
    BAR();                                                                   \
  } while (0)

  // ---- prologue: stage tiles 0,1,2; wait for tile 0 (8 loads stay in flight) ----
  SCALL(0, 0, 0); SCALL(0, 0, 1); SCALL(0, 0, 2); SCALL(0, 0, 3);
  SCALL(1, 1, 0); SCALL(1, 1, 1); SCALL(1, 1, 2); SCALL(1, 1, 3);
  SCALL(2, 2, 0); SCALL(2, 2, 1); SCALL(2, 2, 2); SCALL(2, 2, 3);
  asm volatile("s_waitcnt vmcnt(8)" ::: "memory");
  BAR();

  // ---- main loop: T in [0,20), stage T+3, steady vmcnt(8) ----
  for (int Tb = 0; Tb < 20; Tb += 4) {
    PHASE(0, 3, Tb + 3, 1, 8);
    PHASE(1, 0, Tb + 4, 1, 8);
    PHASE(2, 1, Tb + 5, 1, 8);
    PHASE(3, 2, Tb + 6, 1, 8);
  }
  // ---- peeled tail: T=20 (stage 23), 21, 22, 23 ----
  PHASE(0, 3, 23, 1, 8);
  PHASE(1, 0, 0, 0, 4);
  PHASE(2, 0, 0, 0, 0);
  PHASE(3, 0, 0, 0, -1);

#undef PHASE
#undef SCALL

  // ---- epilogue: exp + store + per-row sums (C/D layout: col=lane&15, row=(lane>>4)*4+j) ----
  float rs[8][4];
#pragma unroll
  for (int m = 0; m < 8; m++)
#pragma unroll
    for (int j = 0; j < 4; j++) rs[m][j] = 0.0f;
  const size_t rowBase = rA0 + (size_t)wr * 128;
  const int colBase = tn * 256 + wc * 64;
#pragma unroll
  for (int mi = 0; mi < 8; mi++) {
    size_t row0 = rowBase + mi * 16 + lq * 4;
#pragma unroll
    for (int nf = 0; nf < 4; nf++) {
      int col = colBase + nf * 16 + lr;
#pragma unroll
      for (int j = 0; j < 4; j++) {
        float e = __expf(acc[mi][nf][j] * scale);
        C[(row0 + j) * 8192 + col] = f2bf(e);
        rs[mi][j] += e;
      }
    }
  }
#pragma unroll
  for (int mi = 0; mi < 8; mi++)
#pragma unroll
    for (int j = 0; j < 4; j++) {
      float r = rs[mi][j];
      r += __shfl_xor(r, 1); r += __shfl_xor(r, 2);
      r += __shfl_xor(r, 4); r += __shfl_xor(r, 8);
      if (lr == 0) atomicAdd(&rowsum[rowBase + mi * 16 + lq * 4 + j], r);
    }
}

// ---------------- bt-GEMM (m97 128^2 structure) for qkv / PV / proj ----------------
// MODE 0: bf16 out * scale; MODE 2: f32 out + bias[col]
template <int MODE>
__global__ __launch_bounds__(256, 2) void gemm_bt(
    const u16* __restrict__ A0, const u16* __restrict__ B0,
    void* __restrict__ Cv0, void* __restrict__ Cv1,
    int M, int N, int K, int lda, int ldb, int ldc,
    float scale, const float* __restrict__ bias, size_t cSplitStride) {
  __shared__ __align__(16) u16 sA[128 * 64];
  __shared__ __align__(16) u16 sB[128 * 64];
  const int z = blockIdx.y;
  const u16* A = A0 + (size_t)z * (size_t)K;
  const u16* B = B0 + (size_t)z * (size_t)K;
  u16* Cb = (z < 2) ? ((u16*)Cv0 + (size_t)z * cSplitStride)
                    : ((u16*)Cv1 + (size_t)(z - 2) * cSplitStride);
  const int nTn = N >> 7;
  int nwg = gridDim.x, orig = blockIdx.x;
  int qq = nwg >> 3, rr = nwg & 7;
  int xcd = orig & 7, loc = orig >> 3;
  int wg = (xcd < rr ? xcd * (qq + 1) : rr * (qq + 1) + (xcd - rr) * qq) + loc;
  int tm = wg / nTn, tn = wg % nTn;

  const int t = threadIdx.x, l = t & 63, w = t >> 6;
  const int wr = w >> 1, wc = w & 1;
  const int lr = l & 15, kg = (l >> 4) << 3;

  f32x4 acc[4][4];
#pragma unroll
  for (int m = 0; m < 4; m++)
#pragma unroll
    for (int n = 0; n < 4; n++) acc[m][n] = (f32x4){0.f, 0.f, 0.f, 0.f};

  const size_t rowA0 = (size_t)tm * 128;
  const size_t rowB0 = (size_t)tn * 128;
  const int nk = K >> 6;
  for (int kt = 0; kt < nk; kt++) {
    const int k0 = kt << 6;
#pragma unroll
    for (int i = 0; i < 4; i++) {
      int chunk = i * 256 + t;
      int row = chunk >> 3;
      int col = (chunk & 7) << 3;
      gload_lds16(A + (rowA0 + row) * lda + k0 + col, (const char*)sA + (i * 256 + w * 64) * 16);
      gload_lds16(B + (rowB0 + row) * ldb + k0 + col, (const char*)sB + (i * 256 + w * 64) * 16);
    }
    __syncthreads();
#pragma unroll
    for (int kk = 0; kk < 2; kk++) {
      bf16x8 af[4], bfv[4];
#pragma unroll
      for (int m = 0; m < 4; m++)
        af[m] = *(const bf16x8*)&sA[(wr * 64 + m * 16 + lr) * 64 + kk * 32 + kg];
#pragma unroll
      for (int n = 0; n < 4; n++)
        bfv[n] = *(const bf16x8*)&sB[(wc * 64 + n * 16 + lr) * 64 + kk * 32 + kg];
#pragma unroll
      for (int m = 0; m < 4; m++)
#pragma unroll
        for (int n = 0; n < 4; n++)
          acc[m][n] = __builtin_amdgcn_mfma_f32_16x16x32_bf16(af[m], bfv[n], acc[m][n], 0, 0, 0);
    }
    __syncthreads();
  }
#pragma unroll
  for (int m = 0; m < 4; m++) {
    int row = tm * 128 + wr * 64 + m * 16 + ((l >> 4) << 2);
#pragma unroll
    for (int n = 0; n < 4; n++) {
      int col = tn * 128 + wc * 64 + n * 16 + lr;
#pragma unroll
      for (int j = 0; j < 4; j++) {
        float vl = acc[m][n][j];
        if (MODE == 0) Cb[(size_t)(row + j) * ldc + col] = f2bf(vl * scale);
        else ((float*)Cv0)[(size_t)(row + j) * ldc + col] = vl + bias[col];
      }
    }
  }
}

// ---------------- host ----------------
extern "C" void kernel_launch(void* const* d_in, const int* in_sizes, int n_in,
                              void* d_out, int out_size, void* d_ws, size_t ws_size,
                              hipStream_t stream) {
  const float* q  = (const float*)d_in[0];
  const float* k  = (const float*)d_in[1];
  const float* v  = (const float*)d_in[2];
  const float* lw = (const float*)d_in[3];
  const float* lb = (const float*)d_in[4];
  const float* Wq = (const float*)d_in[5];
  const float* Wp = (const float*)d_in[6];
  const float* bp = (const float*)d_in[7];

  char* ws = (char*)d_ws;
  size_t off = 0;
  auto alloc = [&](size_t b) { size_t o = off; off += (b + 255) & ~(size_t)255; return o; };
  size_t o_ln = alloc((size_t)24576 * 768 * 2);  // LN(q,k,v) bf16; later: vnT | p0 | p1
  size_t o_pj = alloc((size_t)24576 * 768 * 2);  // qn,kn,vn bf16; vn region later: rowsum
  size_t o_wq = alloc((size_t)768 * 768 * 2);
  size_t o_wp = alloc((size_t)768 * 768 * 2);
  u16* lnbuf = (u16*)(ws + o_ln);
  u16* pj    = (u16*)(ws + o_pj);
  u16* wqb   = (u16*)(ws + o_wq);
  u16* wpb   = (u16*)(ws + o_wp);
  const size_t NS = (size_t)8192 * 768;
  u16* vnT = lnbuf;
  u16* p0  = lnbuf + NS;
  u16* p1  = lnbuf + 2 * NS;
  float* rowsum = (float*)(pj + 2 * NS);  // vn rows dead after transpose
  u16* p2 = (u16*)d_out;                   // partials 2,3 in d_out (overwritten by proj)
  u16* p3 = p2 + NS;
  size_t fixedEnd = off;
  u16* Sbuf = (u16*)(ws + fixedEnd);       // P' = exp(S*scale) bf16, 8192x8192

  const float scale = 0.03608439182435161f;  // 1/sqrt(768)

  ln_cast_kernel<<<dim3(24576), dim3(256), 0, stream>>>(q, k, v, lw, lb, lnbuf);
  cast_f32_bf16<<<dim3(576), dim3(256), 0, stream>>>(Wq, wqb, 147456);
  cast_f32_bf16<<<dim3(576), dim3(256), 0, stream>>>(Wp, wpb, 147456);

  // qn/kn/vn = LN(x) @ W_qkv^T
  gemm_bt<0><<<dim3(1152), dim3(256), 0, stream>>>(lnbuf, wqb, (void*)pj, (void*)pj,
      24576, 768, 768, 768, 768, 768, 1.0f, (const float*)nullptr, 0);

  transpose64<<<dim3(1536), dim3(256), 0, stream>>>(pj + (size_t)16384 * 768, vnT);
  zero_f32<<<dim3(32), dim3(256), 0, stream>>>(rowsum, 8192);

  // P' = exp(qn @ kn^T * scale), rowsum via atomics — stage-ahead-3 counted-vmcnt kernel
  qk_exp_256<<<dim3(1024), dim3(512), 0, stream>>>(pj, pj + NS, Sbuf, rowsum, scale);

  // attn partials = P' @ vn, 4-way split-K
  gemm_bt<0><<<dim3(384, 4), dim3(256), 0, stream>>>(
      Sbuf, vnT, (void*)p0, (void*)p2,
      8192, 768, 2048, 8192, 8192, 768, 1.0f, (const float*)nullptr, NS);

  // attn_out = (p0+p1+p2+p3) / rowsum
  reduce4_scale<<<dim3(3072), dim3(256), 0, stream>>>(p0, p1, p2, p3, rowsum, p0, (int)(NS / 8));

  // out = attn_out @ W_proj^T + b_proj
  gemm_bt<2><<<dim3(384), dim3(256), 0, stream>>>(p0, wpb, d_out, d_out,
      8192, 768, 768, 768, 768, 768, 1.0f, bp, 0);
}

// Round 9
// 358.842 us; speedup vs baseline: 1.1103x; 1.0016x over previous
//
#include <hip/hip_runtime.h>
#include <hip/hip_bf16.h>
#include <stdint.h>

typedef short bf16x8 __attribute__((ext_vector_type(8)));   // 8 bf16 in 4 VGPRs
typedef float f32x4 __attribute__((ext_vector_type(4)));
typedef unsigned short u16;
typedef u16 u16x8 __attribute__((ext_vector_type(8)));

__device__ __forceinline__ u16 f2bf(float x) {
  __hip_bfloat16 h = __float2bfloat16(x);
  return *reinterpret_cast<u16*>(&h);
}
__device__ __forceinline__ float bf2f(u16 v) {
  unsigned u = (unsigned)v << 16;
  return *reinterpret_cast<float*>(&u);
}

// async global->LDS, 16B per lane. LDS dest is wave-uniform base + lane*16 (m104/m108).
__device__ __forceinline__ void gload_lds16(const void* g, const void* lds_base) {
  __builtin_amdgcn_global_load_lds(
      (const __attribute__((address_space(1))) unsigned int*)(uintptr_t)g,
      (__attribute__((address_space(3))) unsigned int*)(uintptr_t)lds_base,
      16, 0, 0);
}

#define BAR() __builtin_amdgcn_s_barrier()

// ---------------- LayerNorm + cast to bf16 (rows of q,k,v), float4-vectorized ----------------
__global__ __launch_bounds__(256) void ln_cast_kernel(
    const float* __restrict__ q, const float* __restrict__ k, const float* __restrict__ v,
    const float* __restrict__ lw, const float* __restrict__ lb, u16* __restrict__ out) {
  int row = blockIdx.x;
  const float* x;
  if (row < 8192) x = q + (size_t)row * 768;
  else if (row < 16384) x = k + (size_t)(row - 8192) * 768;
  else x = v + (size_t)(row - 16384) * 768;
  int t = threadIdx.x;
  __shared__ float red[4];
  __shared__ float red2[4];
  float4 a = (t < 192) ? ((const float4*)x)[t] : make_float4(0.f, 0.f, 0.f, 0.f);
  float s = a.x + a.y + a.z + a.w;
  for (int o = 32; o; o >>= 1) s += __shfl_down(s, o, 64);
  if ((t & 63) == 0) red[t >> 6] = s;
  __syncthreads();
  float mean = (red[0] + red[1] + red[2]) * (1.0f / 768.0f);
  float4 d = make_float4(a.x - mean, a.y - mean, a.z - mean, a.w - mean);
  float vs = (t < 192) ? (d.x * d.x + d.y * d.y + d.z * d.z + d.w * d.w) : 0.f;
  for (int o = 32; o; o >>= 1) vs += __shfl_down(vs, o, 64);
  if ((t & 63) == 0) red2[t >> 6] = vs;
  __syncthreads();
  float var = (red2[0] + red2[1] + red2[2]) * (1.0f / 768.0f);
  float rstd = rsqrtf(var + 1e-5f);
  if (t < 192) {
    float4 wv = ((const float4*)lw)[t];
    float4 bv = ((const float4*)lb)[t];
    ushort4 o;
    o.x = f2bf(d.x * rstd * wv.x + bv.x);
    o.y = f2bf(d.y * rstd * wv.y + bv.y);
    o.z = f2bf(d.z * rstd * wv.z + bv.z);
    o.w = f2bf(d.w * rstd * wv.w + bv.w);
    ((ushort4*)(out + (size_t)row * 768))[t] = o;
  }
}

// ---------------- fp32 -> bf16 cast (weights) ----------------
__global__ __launch_bounds__(256) void cast_f32_bf16(const float* __restrict__ in,
                                                     u16* __restrict__ out, int n4) {
  int i = blockIdx.x * 256 + threadIdx.x;
  if (i < n4) {
    float4 vv = ((const float4*)in)[i];
    ushort4 o;
    o.x = f2bf(vv.x); o.y = f2bf(vv.y); o.z = f2bf(vv.z); o.w = f2bf(vv.w);
    ((ushort4*)out)[i] = o;
  }
}

// ---------------- zero fp32 buffer ----------------
__global__ __launch_bounds__(256) void zero_f32(float* __restrict__ p, int n) {
  int i = blockIdx.x * 256 + threadIdx.x;
  if (i < n) p[i] = 0.0f;
}

// ---------------- 64x64 tiled bf16 transpose: vn[8192][768] -> vnT[768][8192] ----------------
__global__ __launch_bounds__(256) void transpose64(const u16* __restrict__ in, u16* __restrict__ out) {
  __shared__ __align__(16) u16 tile[64][72];
  int b = blockIdx.x;
  int tr = b / 12, tc = b % 12;
  int t = threadIdx.x;
  int r = t >> 3;
  int cb = (t & 7) << 3;
#pragma unroll
  for (int i = 0; i < 2; i++) {
    int row = r + i * 32;
    const u16* src = in + (size_t)(tr * 64 + row) * 768 + tc * 64 + cb;
    *(uint4*)&tile[row][cb] = *(const uint4*)src;
  }
  __syncthreads();
#pragma unroll
  for (int i = 0; i < 2; i++) {
    int oc = r + i * 32;
    u16x8 tmp;
#pragma unroll
    for (int j = 0; j < 8; j++) tmp[j] = tile[cb + j][oc];
    u16* dst = out + (size_t)(tc * 64 + oc) * 8192 + tr * 64 + cb;
    *(u16x8*)dst = tmp;
  }
}

// ---------------- sum 4 bf16 partials, scale by 1/rowsum, write bf16 ----------------
__global__ __launch_bounds__(256) void reduce4_scale(
    const u16* __restrict__ p0, const u16* __restrict__ p1,
    const u16* __restrict__ p2, const u16* __restrict__ p3,
    const float* __restrict__ rowsum, u16* __restrict__ out, int n8) {
  int i = blockIdx.x * 256 + threadIdx.x;
  if (i < n8) {
    float inv = 1.0f / rowsum[i / 96];
    u16x8 a = ((const u16x8*)p0)[i];
    u16x8 b = ((const u16x8*)p1)[i];
    u16x8 c = ((const u16x8*)p2)[i];
    u16x8 d = ((const u16x8*)p3)[i];
    u16x8 o;
#pragma unroll
    for (int j = 0; j < 8; j++)
      o[j] = f2bf((bf2f(a[j]) + bf2f(b[j]) + bf2f(c[j]) + bf2f(d[j])) * inv);
    ((u16x8*)out)[i] = o;
  }
}

// ========== QK^T + exp, 256x256 tile, BK=32, 4-deep rotation, stage-ahead-3 ==========
// Round-9 change: ALL 12 ds_reads issued at phase start (before BAR — data arrives during
// barrier sync), 32 MFMA as ONE contiguous setprio cluster (removes mid-phase lgkm bubble).
// Hazards unchanged from round 8 (proved): RAW via vmcnt(8) at prior phase end; WAR via
// buf last-read one phase before stage-issue. Single merged LDS array (A @0, B @64KB).
__global__ __launch_bounds__(512, 2) void qk_exp_256(
    const u16* __restrict__ A, const u16* __restrict__ B, u16* __restrict__ C,
    float* __restrict__ rowsum, float scale) {
  __shared__ __align__(16) u16 lds[8 * 256 * 32];  // 128 KB: A bufs 0-3 | B bufs 0-3
  int orig = blockIdx.x;               // 1024 blocks, %8==0
  int xcd = orig & 7, i = orig >> 3;
  int tm = xcd * 4 + (i & 3), tn = i >> 2;
  const int t = threadIdx.x, l = t & 63, w = t >> 6;
  const int wr = w >> 2, wc = w & 3;   // 2 x 4 wave grid
  const int lr = l & 15, lq = l >> 4;
  const int colb = lq * 16;

  f32x4 acc[8][4];
#pragma unroll
  for (int m = 0; m < 8; m++)
#pragma unroll
    for (int n = 0; n < 4; n++) acc[m][n] = (f32x4){0.f, 0.f, 0.f, 0.f};

  const size_t rA0 = (size_t)tm * 256, rB0 = (size_t)tn * 256;

  // ---- hoisted addressing ----
  const char* gsrc[4];
  int ldsoff[4];
#pragma unroll
  for (int idx = 0; idx < 4; idx++) {
    const u16* src = (idx < 2) ? A : B;
    size_t r0 = (idx < 2) ? rA0 : rB0;
    int p = idx & 1;
    int x = p * 8192 + t * 16;
    int r = x >> 6;
    int cb = (x & 63) ^ (((r >> 1) & 3) << 4);
    gsrc[idx] = (const char*)(src + (r0 + r) * 768) + cb;
    ldsoff[idx] = ((idx < 2) ? 0 : 65536) + p * 8192 + w * 1024;
  }
  int offA[2][4], offB[4];
#pragma unroll
  for (int mh = 0; mh < 2; mh++)
#pragma unroll
    for (int mf = 0; mf < 4; mf++) {
      int row = wr * 128 + (mh * 4 + mf) * 16 + lr;
      int x = row * 64 + colb;
      offA[mh][mf] = x ^ (((row >> 1) & 3) << 4);
    }
#pragma unroll
  for (int nf = 0; nf < 4; nf++) {
    int row = wc * 64 + nf * 16 + lr;
    int x = row * 64 + colb;
    offB[nf] = 65536 + (x ^ (((row >> 1) & 3) << 4));
  }

#define SCALL(BUF, TT, IDX)                                                  \
  gload_lds16(gsrc[IDX] + (size_t)(TT) * 64,                                 \
              (const char*)lds + (BUF) * 16384 + ldsoff[IDX])

  auto LOADA = [&](bf16x8 (&aF)[4], int b, int mh) {
#pragma unroll
    for (int mf = 0; mf < 4; mf++)
      aF[mf] = *(const bf16x8*)((const char*)lds + b * 16384 + offA[mh][mf]);
  };
  auto LOADB = [&](bf16x8 (&bF)[4], int b) {
#pragma unroll
    for (int nf = 0; nf < 4; nf++)
      bF[nf] = *(const bf16x8*)((const char*)lds + b * 16384 + offB[nf]);
  };
  // one contiguous 32-MFMA cluster under a single setprio window
  auto MM32 = [&](bf16x8 (&aF)[4], bf16x8 (&aG)[4], bf16x8 (&bF)[4]) {
    __builtin_amdgcn_s_setprio(1);
#pragma unroll
    for (int mf = 0; mf < 4; mf++)
#pragma unroll
      for (int nf = 0; nf < 4; nf++)
        acc[mf][nf] = __builtin_amdgcn_mfma_f32_16x16x32_bf16(
            aF[mf], bF[nf], acc[mf][nf], 0, 0, 0);
#pragma unroll
    for (int mf = 0; mf < 4; mf++)
#pragma unroll
      for (int nf = 0; nf < 4; nf++)
        acc[4 + mf][nf] = __builtin_amdgcn_mfma_f32_16x16x32_bf16(
            aG[mf], bF[nf], acc[4 + mf][nf], 0, 0, 0);
    __builtin_amdgcn_s_setprio(0);
  };

#define PHASE(CUR, SBUF, STAGET, DOSTAGE, VMN)                               \
  do {                                                                       \
    bf16x8 aF[4], aG[4], bF[4];                                              \
    LOADA(aF, CUR, 0);                                                       \
    LOADA(aG, CUR, 1);                                                       \
    LOADB(bF, CUR);                                                          \
    if (DOSTAGE) {                                                           \
      SCALL(SBUF, STAGET, 0); SCALL(SBUF, STAGET, 1);                        \
      SCALL(SBUF, STAGET, 2); SCALL(SBUF, STAGET, 3);                        \
    }                                                                        \
    BAR();                                                                   \
    MM32(aF, aG, bF);                                                        \
    if ((VMN) == 8) asm volatile("s_waitcnt vmcnt(8)" ::: "memory");         \
    else if ((VMN) == 4) asm volatile("s_waitcnt vmcnt(4)" ::: "memory");    \
    else if ((VMN) == 0) asm volatile("s_waitcnt vmcnt(0)" ::: "memory");    \
    BAR();                                                                   \
  } while (0)

  // ---- prologue: stage tiles 0,1,2; wait for tile 0 (8 loads stay in flight) ----
  SCALL(0, 0, 0); SCALL(0, 0, 1); SCALL(0, 0, 2); SCALL(0, 0, 3);
  SCALL(1, 1, 0); SCALL(1, 1, 1); SCALL(1, 1, 2); SCALL(1, 1, 3);
  SCALL(2, 2, 0); SCALL(2, 2, 1); SCALL(2, 2, 2); SCALL(2, 2, 3);
  asm volatile("s_waitcnt vmcnt(8)" ::: "memory");
  BAR();

  // ---- main loop: T in [0,20), stage T+3, steady vmcnt(8) ----
  for (int Tb = 0; Tb < 20; Tb += 4) {
    PHASE(0, 3, Tb + 3, 1, 8);
    PHASE(1, 0, Tb + 4, 1, 8);
    PHASE(2, 1, Tb + 5, 1, 8);
    PHASE(3, 2, Tb + 6, 1, 8);
  }
  // ---- peeled tail: T=20 (stage 23), 21, 22, 23 ----
  PHASE(0, 3, 23, 1, 8);
  PHASE(1, 0, 0, 0, 4);
  PHASE(2, 0, 0, 0, 0);
  PHASE(3, 0, 0, 0, -1);

#undef PHASE
#undef SCALL

  // ---- epilogue: exp + store + per-row sums (C/D layout: col=lane&15, row=(lane>>4)*4+j) ----
  float rs[8][4];
#pragma unroll
  for (int m = 0; m < 8; m++)
#pragma unroll
    for (int j = 0; j < 4; j++) rs[m][j] = 0.0f;
  const size_t rowBase = rA0 + (size_t)wr * 128;
  const int colBase = tn * 256 + wc * 64;
#pragma unroll
  for (int mi = 0; mi < 8; mi++) {
    size_t row0 = rowBase + mi * 16 + lq * 4;
#pragma unroll
    for (int nf = 0; nf < 4; nf++) {
      int col = colBase + nf * 16 + lr;
#pragma unroll
      for (int j = 0; j < 4; j++) {
        float e = __expf(acc[mi][nf][j] * scale);
        C[(row0 + j) * 8192 + col] = f2bf(e);
        rs[mi][j] += e;
      }
    }
  }
#pragma unroll
  for (int mi = 0; mi < 8; mi++)
#pragma unroll
    for (int j = 0; j < 4; j++) {
      float r = rs[mi][j];
      r += __shfl_xor(r, 1); r += __shfl_xor(r, 2);
      r += __shfl_xor(r, 4); r += __shfl_xor(r, 8);
      if (lr == 0) atomicAdd(&rowsum[rowBase + mi * 16 + lq * 4 + j], r);
    }
}

// ---------------- bt-GEMM (m97 128^2 structure) for qkv / PV / proj ----------------
// MODE 0: bf16 out * scale; MODE 2: f32 out + bias[col]
template <int MODE>
__global__ __launch_bounds__(256, 2) void gemm_bt(
    const u16* __restrict__ A0, const u16* __restrict__ B0,
    void* __restrict__ Cv0, void* __restrict__ Cv1,
    int M, int N, int K, int lda, int ldb, int ldc,
    float scale, const float* __restrict__ bias, size_t cSplitStride) {
  __shared__ __align__(16) u16 sA[128 * 64];
  __shared__ __align__(16) u16 sB[128 * 64];
  const int z = blockIdx.y;
  const u16* A = A0 + (size_t)z * (size_t)K;
  const u16* B = B0 + (size_t)z * (size_t)K;
  u16* Cb = (z < 2) ? ((u16*)Cv0 + (size_t)z * cSplitStride)
                    : ((u16*)Cv1 + (size_t)(z - 2) * cSplitStride);
  const int nTn = N >> 7;
  int nwg = gridDim.x, orig = blockIdx.x;
  int qq = nwg >> 3, rr = nwg & 7;
  int xcd = orig & 7, loc = orig >> 3;
  int wg = (xcd < rr ? xcd * (qq + 1) : rr * (qq + 1) + (xcd - rr) * qq) + loc;
  int tm = wg / nTn, tn = wg % nTn;

  const int t = threadIdx.x, l = t & 63, w = t >> 6;
  const int wr = w >> 1, wc = w & 1;
  const int lr = l & 15, kg = (l >> 4) << 3;

  f32x4 acc[4][4];
#pragma unroll
  for (int m = 0; m < 4; m++)
#pragma unroll
    for (int n = 0; n < 4; n++) acc[m][n] = (f32x4){0.f, 0.f, 0.f, 0.f};

  const size_t rowA0 = (size_t)tm * 128;
  const size_t rowB0 = (size_t)tn * 128;
  const int nk = K >> 6;
  for (int kt = 0; kt < nk; kt++) {
    const int k0 = kt << 6;
#pragma unroll
    for (int i = 0; i < 4; i++) {
      int chunk = i * 256 + t;
      int row = chunk >> 3;
      int col = (chunk & 7) << 3;
      gload_lds16(A + (rowA0 + row) * lda + k0 + col, (const char*)sA + (i * 256 + w * 64) * 16);
      gload_lds16(B + (rowB0 + row) * ldb + k0 + col, (const char*)sB + (i * 256 + w * 64) * 16);
    }
    __syncthreads();
#pragma unroll
    for (int kk = 0; kk < 2; kk++) {
      bf16x8 af[4], bfv[4];
#pragma unroll
      for (int m = 0; m < 4; m++)
        af[m] = *(const bf16x8*)&sA[(wr * 64 + m * 16 + lr) * 64 + kk * 32 + kg];
#pragma unroll
      for (int n = 0; n < 4; n++)
        bfv[n] = *(const bf16x8*)&sB[(wc * 64 + n * 16 + lr) * 64 + kk * 32 + kg];
#pragma unroll
      for (int m = 0; m < 4; m++)
#pragma unroll
        for (int n = 0; n < 4; n++)
          acc[m][n] = __builtin_amdgcn_mfma_f32_16x16x32_bf16(af[m], bfv[n], acc[m][n], 0, 0, 0);
    }
    __syncthreads();
  }
#pragma unroll
  for (int m = 0; m < 4; m++) {
    int row = tm * 128 + wr * 64 + m * 16 + ((l >> 4) << 2);
#pragma unroll
    for (int n = 0; n < 4; n++) {
      int col = tn * 128 + wc * 64 + n * 16 + lr;
#pragma unroll
      for (int j = 0; j < 4; j++) {
        float vl = acc[m][n][j];
        if (MODE == 0) Cb[(size_t)(row + j) * ldc + col] = f2bf(vl * scale);
        else ((float*)Cv0)[(size_t)(row + j) * ldc + col] = vl + bias[col];
      }
    }
  }
}

// ---------------- host ----------------
extern "C" void kernel_launch(void* const* d_in, const int* in_sizes, int n_in,
                              void* d_out, int out_size, void* d_ws, size_t ws_size,
                              hipStream_t stream) {
  const float* q  = (const float*)d_in[0];
  const float* k  = (const float*)d_in[1];
  const float* v  = (const float*)d_in[2];
  const float* lw = (const float*)d_in[3];
  const float* lb = (const float*)d_in[4];
  const float* Wq = (const float*)d_in[5];
  const float* Wp = (const float*)d_in[6];
  const float* bp = (const float*)d_in[7];

  char* ws = (char*)d_ws;
  size_t off = 0;
  auto alloc = [&](size_t b) { size_t o = off; off += (b + 255) & ~(size_t)255; return o; };
  size_t o_ln = alloc((size_t)24576 * 768 * 2);  // LN(q,k,v) bf16; later: vnT | p0 | p1
  size_t o_pj = alloc((size_t)24576 * 768 * 2);  // qn,kn,vn bf16; vn region later: rowsum
  size_t o_wq = alloc((size_t)768 * 768 * 2);
  size_t o_wp = alloc((size_t)768 * 768 * 2);
  u16* lnbuf = (u16*)(ws + o_ln);
  u16* pj    = (u16*)(ws + o_pj);
  u16* wqb   = (u16*)(ws + o_wq);
  u16* wpb   = (u16*)(ws + o_wp);
  const size_t NS = (size_t)8192 * 768;
  u16* vnT = lnbuf;
  u16* p0  = lnbuf + NS;
  u16* p1  = lnbuf + 2 * NS;
  float* rowsum = (float*)(pj + 2 * NS);  // vn rows dead after transpose
  u16* p2 = (u16*)d_out;                   // partials 2,3 in d_out (overwritten by proj)
  u16* p3 = p2 + NS;
  size_t fixedEnd = off;
  u16* Sbuf = (u16*)(ws + fixedEnd);       // P' = exp(S*scale) bf16, 8192x8192

  const float scale = 0.03608439182435161f;  // 1/sqrt(768)

  ln_cast_kernel<<<dim3(24576), dim3(256), 0, stream>>>(q, k, v, lw, lb, lnbuf);
  cast_f32_bf16<<<dim3(576), dim3(256), 0, stream>>>(Wq, wqb, 147456);
  cast_f32_bf16<<<dim3(576), dim3(256), 0, stream>>>(Wp, wpb, 147456);

  // qn/kn/vn = LN(x) @ W_qkv^T
  gemm_bt<0><<<dim3(1152), dim3(256), 0, stream>>>(lnbuf, wqb, (void*)pj, (void*)pj,
      24576, 768, 768, 768, 768, 768, 1.0f, (const float*)nullptr, 0);

  transpose64<<<dim3(1536), dim3(256), 0, stream>>>(pj + (size_t)16384 * 768, vnT);
  zero_f32<<<dim3(32), dim3(256), 0, stream>>>(rowsum, 8192);

  // P' = exp(qn @ kn^T * scale), rowsum via atomics — stage-ahead-3, hoisted-read kernel
  qk_exp_256<<<dim3(1024), dim3(512), 0, stream>>>(pj, pj + NS, Sbuf, rowsum, scale);

  // attn partials = P' @ vn, 4-way split-K
  gemm_bt<0><<<dim3(384, 4), dim3(256), 0, stream>>>(
      Sbuf, vnT, (void*)p0, (void*)p2,
      8192, 768, 2048, 8192, 8192, 768, 1.0f, (const float*)nullptr, NS);

  // attn_out = (p0+p1+p2+p3) / rowsum
  reduce4_scale<<<dim3(3072), dim3(256), 0, stream>>>(p0, p1, p2, p3, rowsum, p0, (int)(NS / 8));

  // out = attn_out @ W_proj^T + b_proj
  gemm_bt<2><<<dim3(384), dim3(256), 0, stream>>>(p0, wpb, d_out, d_out,
      8192, 768, 768, 768, 768, 768, 1.0f, bp, 0);
}